// Round 1
// baseline (574.361 us; speedup 1.0000x reference)
//
#include <hip/hip_runtime.h>
#include <cstdint>
#include <cstddef>

typedef float f32x4 __attribute__((ext_vector_type(4)));
typedef short s16x8 __attribute__((ext_vector_type(8)));
typedef short s16x4 __attribute__((ext_vector_type(4)));

#define DEV static __device__ __forceinline__

DEV float bf2f(short s) {
  union { unsigned u; float f; } c;
  c.u = ((unsigned)(unsigned short)s) << 16;
  return c.f;
}
DEV short f2bf(float f) {
  union { float f; unsigned u; } c;
  c.f = f;
  unsigned r = c.u + 0x7fffu + ((c.u >> 16) & 1u);
  return (short)(r >> 16);
}
DEV float wave_allsum(float v) {
#pragma unroll
  for (int off = 32; off > 0; off >>= 1) v += __shfl_xor(v, off, 64);
  return v;
}
DEV void gload_lds16(const void* g, void* l) {
  __builtin_amdgcn_global_load_lds(
      (const __attribute__((address_space(1))) void*)g,
      (__attribute__((address_space(3))) void*)l, 16, 0, 0);
}
DEV float silu_f(float g) { return g / (1.f + __expf(-g)); }

// ---------------- bf16 GEMM: C = A(MxK) @ W(NxK)^T, various fused epilogues ----
// 128x128 tile, BK=64, 4 waves, global_load_lds(16B) staging, XOR k-group swizzle
// (linear LDS dest + inverse-swizzled global src + swizzled ds_read — rule #21).
enum { EPI_BF16 = 0, EPI_BIAS_BF16 = 1, EPI_SILU = 2, EPI_F32 = 3, EPI_SCATTER = 4 };

template <int EPI>
__global__ __launch_bounds__(256) void gemm_bt(
    const short* __restrict__ A, const short* __restrict__ W,
    const float* __restrict__ bias, void* __restrict__ outp,
    const short* __restrict__ gate, int M, int N, int K)
{
  __shared__ short As[128 * 64];
  __shared__ short Bs[128 * 64];
  const int tid = threadIdx.x;
  const int wave = tid >> 6, lane = tid & 63;
  const int row0 = blockIdx.y * 128, col0 = blockIdx.x * 128;
  const int wr = wave >> 1, wc = wave & 1;

  f32x4 acc[4][4];
#pragma unroll
  for (int m = 0; m < 4; ++m)
#pragma unroll
    for (int n = 0; n < 4; ++n) acc[m][n] = f32x4{0.f, 0.f, 0.f, 0.f};

  // staging geometry: issue i covers LDS elements [i*2048 + tid*8, +8)
  int srow[4], skg[4];
#pragma unroll
  for (int i = 0; i < 4; ++i) {
    int e = i * 2048 + tid * 8;
    srow[i] = e >> 6;                          // tile row (64 bf16 per row)
    skg[i] = ((e >> 3) & 7) ^ (srow[i] & 7);   // inverse-swizzled source k-group
  }

  for (int kt = 0; kt < K; kt += 64) {
#pragma unroll
    for (int i = 0; i < 4; ++i)
      gload_lds16(A + (size_t)(row0 + srow[i]) * K + kt + skg[i] * 8,
                  &As[i * 2048 + wave * 512]);
#pragma unroll
    for (int i = 0; i < 4; ++i)
      gload_lds16(W + (size_t)(col0 + srow[i]) * K + kt + skg[i] * 8,
                  &Bs[i * 2048 + wave * 512]);
    __syncthreads();
#pragma unroll
    for (int ks = 0; ks < 2; ++ks) {
      s16x8 af[4], bfr[4];
#pragma unroll
      for (int m = 0; m < 4; ++m) {
        int row = wr * 64 + m * 16 + (lane & 15);
        int kg = (ks * 4 + (lane >> 4)) ^ (row & 7);
        af[m] = *(const s16x8*)&As[row * 64 + kg * 8];
      }
#pragma unroll
      for (int n = 0; n < 4; ++n) {
        int col = wc * 64 + n * 16 + (lane & 15);
        int kg = (ks * 4 + (lane >> 4)) ^ (col & 7);
        bfr[n] = *(const s16x8*)&Bs[col * 64 + kg * 8];
      }
#pragma unroll
      for (int m = 0; m < 4; ++m)
#pragma unroll
        for (int n = 0; n < 4; ++n)
          acc[m][n] = __builtin_amdgcn_mfma_f32_16x16x32_bf16(af[m], bfr[n], acc[m][n], 0, 0, 0);
    }
    __syncthreads();
  }

  const int lr = (lane >> 4) * 4, lc = lane & 15;
#pragma unroll
  for (int m = 0; m < 4; ++m) {
#pragma unroll
    for (int i = 0; i < 4; ++i) {
      int gr = row0 + wr * 64 + m * 16 + lr + i;
      size_t orow;
      if (EPI == EPI_SCATTER) {
        // window row (b,w,n) -> rolled grid (ry,rx) -> roll back (+1,+1)
        int b = gr / 900, rem = gr % 900;
        int w = rem / 9, n_ = rem % 9;
        int wi = w / 10, wj = w % 10;
        int ii = n_ / 3, jj = n_ % 3;
        int gy = wi * 3 + ii + 1; if (gy >= 30) gy -= 30;
        int gx = wj * 3 + jj + 1; if (gx >= 30) gx -= 30;
        orow = (size_t)b * 900 + gy * 30 + gx;
      } else {
        orow = (size_t)gr;
      }
#pragma unroll
      for (int n = 0; n < 4; ++n) {
        int gc = col0 + wc * 64 + n * 16 + lc;
        float v = acc[m][n][i];
        if (EPI == EPI_BIAS_BF16 || EPI == EPI_SCATTER) v += bias[gc];
        if (EPI == EPI_SILU) {
          float gval = bf2f(gate[(size_t)gr * N + gc]);
          v *= silu_f(gval);
        }
        if (EPI == EPI_BF16 || EPI == EPI_BIAS_BF16 || EPI == EPI_SILU)
          ((short*)outp)[orow * (size_t)N + gc] = f2bf(v);
        else
          ((float*)outp)[orow * (size_t)N + gc] = v;
      }
    }
  }
}

// ---------------- weight / activation conversion ----------------
__global__ __launch_bounds__(256) void cvt4_kernel(const float* __restrict__ src,
                                                   short* __restrict__ dst, int n4) {
  int i = blockIdx.x * 256 + threadIdx.x;
  if (i >= n4) return;
  f32x4 v = *(const f32x4*)(src + (size_t)i * 4);
  s16x4 o;
#pragma unroll
  for (int e = 0; e < 4; ++e) o[e] = f2bf(v[e]);
  *(s16x4*)(dst + (size_t)i * 4) = o;
}

// prefix rows (b in [0,32), t in [0,16)) -> bf16 (512x512)
__global__ __launch_bounds__(256) void prefix_cvt_kernel(const float* __restrict__ hs,
                                                         short* __restrict__ dst) {
  int i = blockIdx.x * 256 + threadIdx.x;  // 512*128 float4 tasks
  if (i >= 512 * 128) return;
  int r = i >> 7, c4 = i & 127;
  int b = r >> 4, t = r & 15;
  f32x4 v = *(const f32x4*)(hs + ((size_t)b * 916 + t) * 512 + c4 * 4);
  s16x4 o;
#pragma unroll
  for (int e = 0; e < 4; ++e) o[e] = f2bf(v[e]);
  *(s16x4*)(dst + (size_t)r * 512 + c4 * 4) = o;
}

// per-batch mean of 16 prefix tokens
__global__ __launch_bounds__(512) void mean_kernel(const float* __restrict__ hs,
                                                   float* __restrict__ m) {
  int b = blockIdx.x, d = threadIdx.x;
  float s = 0.f;
#pragma unroll
  for (int t = 0; t < 16; ++t) s += hs[((size_t)b * 916 + t) * 512 + d];
  m[b * 512 + d] = s * (1.f / 16.f);
}

// grid = hs[:,16:] + mean ; store fp32 residual (b,gy,gx) and bf16 window-partitioned
// rolled copy xw[(b,wi,wj,i,j)][d]
__global__ __launch_bounds__(256) void prep_kernel(const float* __restrict__ hs,
                                                   const float* __restrict__ m,
                                                   float* __restrict__ gridf,
                                                   short* __restrict__ xw) {
  int idx = blockIdx.x * 256 + threadIdx.x;
  if (idx >= 32 * 900 * 128) return;
  int c4 = idx & 127;
  int row = idx >> 7;
  int b = row / 900, rem = row % 900;
  int gy = rem / 30, gx = rem % 30;
  f32x4 v = *(const f32x4*)(hs + ((size_t)b * 916 + 16 + rem) * 512 + c4 * 4);
  f32x4 mm = *(const f32x4*)(m + b * 512 + c4 * 4);
  v += mm;
  *(f32x4*)(gridf + (size_t)row * 512 + c4 * 4) = v;
  int ry = gy + 29; if (ry >= 30) ry -= 30;   // (gy-1) mod 30
  int rx = gx + 29; if (rx >= 30) rx -= 30;
  int wi = ry / 3, ii = ry % 3, wj = rx / 3, jj = rx % 3;
  size_t xrow = (size_t)((b * 100 + wi * 10 + wj) * 9 + ii * 3 + jj);
  s16x4 o;
#pragma unroll
  for (int e = 0; e < 4; ++e) o[e] = f2bf(v[e]);
  *(s16x4*)(xw + xrow * 512 + c4 * 4) = o;
}

// ---------------- windowed attention (9 tokens, 8 heads per window) ----------
__global__ __launch_bounds__(256) void attn_kernel(const short* __restrict__ qkv,
                                                   const float* __restrict__ rel_bias,
                                                   short* __restrict__ outp) {
  __shared__ short sq[9 * 512];
  __shared__ short sk[9 * 512];
  __shared__ short sv[9 * 512];
  __shared__ float sS[648];
  const int wlin = blockIdx.x;        // b*100 + w
  const int w = wlin % 100;
  const int wi = w / 10, wj = w % 10;
  const int tid = threadIdx.x;
  const short* base = qkv + (size_t)wlin * 9 * 1536;
  for (int idx = tid; idx < 1728; idx += 256) {
    int n = idx / 192, c8 = idx % 192;
    s16x8 v = *(const s16x8*)(base + (size_t)n * 1536 + c8 * 8);
    int which = c8 >> 6;
    short* dst = (which == 0) ? sq : (which == 1) ? sk : sv;
    *(s16x8*)(dst + n * 512 + (c8 & 63) * 8) = v;
  }
  __syncthreads();
  // scores + rel bias + shift mask
  for (int idx = tid; idx < 648; idx += 256) {
    int h = idx / 81, r = idx % 81, i = r / 9, j = r % 9;
    const short* qp = sq + i * 512 + h * 64;
    const short* kp = sk + j * 512 + h * 64;
    float dot = 0.f;
#pragma unroll
    for (int c = 0; c < 8; ++c) {
      s16x8 qv = *(const s16x8*)(qp + c * 8);
      s16x8 kv = *(const s16x8*)(kp + c * 8);
#pragma unroll
      for (int e = 0; e < 8; ++e) dot += bf2f(qv[e]) * bf2f(kv[e]);
    }
    float s = dot * 0.125f;
    int ia = i / 3, ja = i % 3, ib = j / 3, jb = j % 3;
    s += rel_bias[(5 * (ia - ib + 2) + (ja - jb + 2)) * 8 + h];
    int ra = wi * 3 + ia, ca = wj * 3 + ja, rb = wi * 3 + ib, cb = wj * 3 + jb;
    int rga = (ra < 27) ? 0 : (ra < 29) ? 1 : 2;
    int cga = (ca < 27) ? 0 : (ca < 29) ? 1 : 2;
    int rgb = (rb < 27) ? 0 : (rb < 29) ? 1 : 2;
    int cgb = (cb < 27) ? 0 : (cb < 29) ? 1 : 2;
    if (rga * 3 + cga != rgb * 3 + cgb) s -= 100.f;
    sS[idx] = s;
  }
  __syncthreads();
  if (tid < 72) {  // softmax per (h,i) row
    float* row = sS + tid * 9;
    float mx = row[0];
#pragma unroll
    for (int j = 1; j < 9; ++j) mx = fmaxf(mx, row[j]);
    float e[9], sum = 0.f;
#pragma unroll
    for (int j = 0; j < 9; ++j) { e[j] = __expf(row[j] - mx); sum += e[j]; }
    float inv = 1.f / sum;
#pragma unroll
    for (int j = 0; j < 9; ++j) row[j] = e[j] * inv;
  }
  __syncthreads();
  // out[h][i][d] = sum_j p * v
  for (int idx = tid; idx < 576; idx += 256) {
    int h = idx / 72, r = idx % 72, i = r / 8, d8 = r % 8;
    const float* p = sS + (h * 9 + i) * 9;
    float a[8] = {0, 0, 0, 0, 0, 0, 0, 0};
#pragma unroll
    for (int j = 0; j < 9; ++j) {
      float pj = p[j];
      s16x8 vv = *(const s16x8*)(sv + j * 512 + h * 64 + d8 * 8);
#pragma unroll
      for (int e = 0; e < 8; ++e) a[e] += pj * bf2f(vv[e]);
    }
    s16x8 o;
#pragma unroll
    for (int e = 0; e < 8; ++e) o[e] = f2bf(a[e]);
    *(s16x8*)(outp + ((size_t)wlin * 9 + i) * 512 + h * 64 + d8 * 8) = o;
  }
}

// ---------------- add + RMS norm variants (one wave per row of 512) ---------
__global__ __launch_bounds__(64) void addnorm1_kernel(const float* __restrict__ g,
                                                      const float* __restrict__ p,
                                                      float* __restrict__ out,
                                                      short* __restrict__ hsb) {
  int row = blockIdx.x, lane = threadIdx.x;  // row = (b, gy*30+gx)
  size_t off = (size_t)row * 512;
  f32x4 x[2];
  float ss = 0.f;
#pragma unroll
  for (int i = 0; i < 2; ++i) {
    f32x4 a = *(const f32x4*)(g + off + i * 256 + lane * 4);
    f32x4 b = *(const f32x4*)(p + off + i * 256 + lane * 4);
    a += b;
    x[i] = a;
    ss += a[0] * a[0] + a[1] * a[1] + a[2] * a[2] + a[3] * a[3];
  }
  ss = wave_allsum(ss);
  float sc = rsqrtf(ss * (1.f / 512.f) + 1e-5f);
  int b_ = row / 900, t = row % 900;
  size_t orow = ((size_t)b_ * 916 + 16 + t) * 512;
#pragma unroll
  for (int i = 0; i < 2; ++i) {
    f32x4 y = x[i] * sc;
    *(f32x4*)(out + orow + i * 256 + lane * 4) = y;
    s16x4 o;
#pragma unroll
    for (int e = 0; e < 4; ++e) o[e] = f2bf(y[e]);
    *(s16x4*)(hsb + orow + i * 256 + lane * 4) = o;
  }
}

__global__ __launch_bounds__(64) void prefix_addnorm_kernel(const float* __restrict__ hs,
                                                            const float* __restrict__ pd,
                                                            float* __restrict__ out,
                                                            short* __restrict__ hsb) {
  int r = blockIdx.x, lane = threadIdx.x;  // r in [0,512)
  int b = r >> 4, t = r & 15;
  size_t orow = ((size_t)b * 916 + t) * 512;
  f32x4 x[2];
  float ss = 0.f;
#pragma unroll
  for (int i = 0; i < 2; ++i) {
    f32x4 a = *(const f32x4*)(hs + orow + i * 256 + lane * 4);
    f32x4 d = *(const f32x4*)(pd + (size_t)r * 512 + i * 256 + lane * 4);
    a += d;
    x[i] = a;
    ss += a[0] * a[0] + a[1] * a[1] + a[2] * a[2] + a[3] * a[3];
  }
  ss = wave_allsum(ss);
  float sc = rsqrtf(ss * (1.f / 512.f) + 1e-5f);
#pragma unroll
  for (int i = 0; i < 2; ++i) {
    f32x4 y = x[i] * sc;
    *(f32x4*)(out + orow + i * 256 + lane * 4) = y;
    s16x4 o;
#pragma unroll
    for (int e = 0; e < 4; ++e) o[e] = f2bf(y[e]);
    *(s16x4*)(hsb + orow + i * 256 + lane * 4) = o;
  }
}

__global__ __launch_bounds__(64) void final_addnorm_kernel(const float* __restrict__ dn,
                                                           float* __restrict__ io) {
  int row = blockIdx.x, lane = threadIdx.x;
  size_t off = (size_t)row * 512;
  f32x4 x[2];
  float ss = 0.f;
#pragma unroll
  for (int i = 0; i < 2; ++i) {
    f32x4 a = *(const f32x4*)(io + off + i * 256 + lane * 4);
    f32x4 d = *(const f32x4*)(dn + off + i * 256 + lane * 4);
    a += d;
    x[i] = a;
    ss += a[0] * a[0] + a[1] * a[1] + a[2] * a[2] + a[3] * a[3];
  }
  ss = wave_allsum(ss);
  float sc = rsqrtf(ss * (1.f / 512.f) + 1e-5f);
#pragma unroll
  for (int i = 0; i < 2; ++i)
    *(f32x4*)(io + off + i * 256 + lane * 4) = x[i] * sc;
}

// ---------------- workspace layout (bytes; liveness-overlaid) ----------------
// requires ws_size >= ~227 MB
static constexpr size_t OFF_WQKV   = 0;                       // 3*512*512*2
static constexpr size_t OFF_WPROJ  = 1572864;                 // 512*512*2
static constexpr size_t OFF_WGU    = 2097152;                 // 3072*512*2
static constexpr size_t OFF_WDOWN  = 5242880;                 // 512*1536*2
static constexpr size_t OFF_WPGU   = 6815744;                 // 3072*512*2
static constexpr size_t OFF_WPDOWN = 9961472;                 // 512*1536*2
static constexpr size_t OFF_MEAN   = 11534336;                // 32*512*4
static constexpr size_t OFF_PREFB  = 11599872;                // 512*512*2
static constexpr size_t OFF_GATEP  = 12124160;                // 512*1536*2
static constexpr size_t OFF_PINTER = 13697024;                // 512*1536*2
static constexpr size_t OFF_PDOUT  = 15269888;                // 512*512*4
static constexpr size_t OFF_GRIDF  = 16777216;                // 28800*512*4
static constexpr size_t OFF_XW     = OFF_GRIDF + 58982400ull; // 28800*512*2
static constexpr size_t OFF_QKV    = OFF_XW + 29491200ull;    // 28800*1536*2
static constexpr size_t OFF_ATTNO  = OFF_XW;                  // reuse (xw dead)
static constexpr size_t OFF_PROJS  = OFF_QKV;                 // reuse (qkv dead)
static constexpr size_t OFF_GATE   = OFF_GRIDF;               // phase2 reuse
static constexpr size_t OFF_INTER  = OFF_GATE + 90046464ull;  // 29312*1536*2
static constexpr size_t OFF_HSB    = OFF_INTER + 90046464ull; // 29312*512*2
static constexpr size_t OFF_DNOUT  = OFF_GATE;                // reuse (gate dead)

extern "C" void kernel_launch(void* const* d_in, const int* in_sizes, int n_in,
                              void* d_out, int out_size, void* d_ws, size_t ws_size,
                              hipStream_t stream) {
  const float* hs      = (const float*)d_in[0];
  const float* qkv_w   = (const float*)d_in[1];
  const float* qkv_b   = (const float*)d_in[2];
  const float* proj_w  = (const float*)d_in[3];
  const float* proj_b  = (const float*)d_in[4];
  const float* rel_b   = (const float*)d_in[5];
  const float* gu_w    = (const float*)d_in[6];
  const float* down_w  = (const float*)d_in[7];
  const float* pgu_w   = (const float*)d_in[8];
  const float* pdown_w = (const float*)d_in[9];

  char* ws = (char*)d_ws;
  short* Wqkv   = (short*)(ws + OFF_WQKV);
  short* Wproj  = (short*)(ws + OFF_WPROJ);
  short* Wgu    = (short*)(ws + OFF_WGU);
  short* Wdown  = (short*)(ws + OFF_WDOWN);
  short* Wpgu   = (short*)(ws + OFF_WPGU);
  short* Wpdown = (short*)(ws + OFF_WPDOWN);
  float* meanb  = (float*)(ws + OFF_MEAN);
  short* prefb  = (short*)(ws + OFF_PREFB);
  short* gatep  = (short*)(ws + OFF_GATEP);
  short* pinter = (short*)(ws + OFF_PINTER);
  float* pdout  = (float*)(ws + OFF_PDOUT);
  float* gridf  = (float*)(ws + OFF_GRIDF);
  short* xw     = (short*)(ws + OFF_XW);
  short* qkvb   = (short*)(ws + OFF_QKV);
  short* attno  = (short*)(ws + OFF_ATTNO);
  float* projs  = (float*)(ws + OFF_PROJS);
  short* gateb  = (short*)(ws + OFF_GATE);
  short* interb = (short*)(ws + OFF_INTER);
  short* hsb    = (short*)(ws + OFF_HSB);
  float* dnout  = (float*)(ws + OFF_DNOUT);
  float* outf   = (float*)d_out;  // also used as fp32 hs scratch (rows fully
                                  // written before the final read-modify-write)

  // 1. weight fp32 -> bf16
  cvt4_kernel<<<768, 256, 0, stream>>>(qkv_w, Wqkv, 786432 / 4);
  cvt4_kernel<<<256, 256, 0, stream>>>(proj_w, Wproj, 262144 / 4);
  cvt4_kernel<<<1536, 256, 0, stream>>>(gu_w, Wgu, 1572864 / 4);
  cvt4_kernel<<<768, 256, 0, stream>>>(down_w, Wdown, 786432 / 4);
  cvt4_kernel<<<1536, 256, 0, stream>>>(pgu_w, Wpgu, 1572864 / 4);
  cvt4_kernel<<<768, 256, 0, stream>>>(pdown_w, Wpdown, 786432 / 4);
  prefix_cvt_kernel<<<256, 256, 0, stream>>>(hs, prefb);

  // 2. prefix mean -> grid residual + rolled/window-partitioned bf16
  mean_kernel<<<32, 512, 0, stream>>>(hs, meanb);
  prep_kernel<<<14400, 256, 0, stream>>>(hs, meanb, gridf, xw);

  // 3. QKV projection (M=28800, N=1536, K=512), +bias, bf16 out
  gemm_bt<EPI_BIAS_BF16><<<dim3(12, 225), 256, 0, stream>>>(xw, Wqkv, qkv_b, qkvb,
                                                            nullptr, 28800, 1536, 512);
  // 4. windowed attention
  attn_kernel<<<3200, 256, 0, stream>>>(qkvb, rel_b, attno);

  // 5. output projection, scatter to un-windowed un-rolled fp32 layout
  gemm_bt<EPI_SCATTER><<<dim3(4, 225), 256, 0, stream>>>(attno, Wproj, proj_b, projs,
                                                         nullptr, 28800, 512, 512);
  // 6. x = rms(residual + proj) -> fp32 rows of d_out + bf16 hs
  addnorm1_kernel<<<28800, 64, 0, stream>>>(gridf, projs, outf, hsb);

  // 7. prefix branch: swiglu + rms
  gemm_bt<EPI_BF16><<<dim3(12, 4), 256, 0, stream>>>(prefb, Wpgu, nullptr, gatep,
                                                     nullptr, 512, 1536, 512);
  gemm_bt<EPI_SILU><<<dim3(12, 4), 256, 0, stream>>>(prefb, Wpgu + 1536 * 512, nullptr,
                                                     pinter, gatep, 512, 1536, 512);
  gemm_bt<EPI_F32><<<dim3(4, 4), 256, 0, stream>>>(pinter, Wpdown, nullptr, pdout,
                                                   nullptr, 512, 512, 1536);
  prefix_addnorm_kernel<<<512, 64, 0, stream>>>(hs, pdout, outf, hsb);

  // 8. full-sequence swiglu (M=29312)
  gemm_bt<EPI_BF16><<<dim3(12, 229), 256, 0, stream>>>(hsb, Wgu, nullptr, gateb,
                                                       nullptr, 29312, 1536, 512);
  gemm_bt<EPI_SILU><<<dim3(12, 229), 256, 0, stream>>>(hsb, Wgu + 1536 * 512, nullptr,
                                                       interb, gateb, 29312, 1536, 512);
  gemm_bt<EPI_F32><<<dim3(4, 229), 256, 0, stream>>>(interb, Wdown, nullptr, dnout,
                                                     nullptr, 29312, 512, 1536);
  // 9. out = rms(hs + down)
  final_addnorm_kernel<<<29312, 64, 0, stream>>>(dnout, outf);

  (void)in_sizes; (void)n_in; (void)out_size; (void)ws_size;
}